// Round 2
// 9961.558 us; speedup vs baseline: 1.1638x; 1.1638x over previous
//
#include <hip/hip_runtime.h>
#include <hip/hip_bf16.h>

#define HDIM 1024
#define G3   3072
#define CHK  16
#define NEG_INF (-__builtin_inff())
#define EB   32   // encoder persistent blocks

typedef unsigned short u16;
typedef unsigned int   u32;

__device__ __forceinline__ float bf2f(u32 h){ union{u32 u; float f;} t; t.u = h<<16; return t.f; }

__device__ __forceinline__ float wred_sum(float v){
  #pragma unroll
  for(int o=32;o;o>>=1) v += __shfl_xor(v,o,64);
  return v;
}
__device__ __forceinline__ float wred_max(float v){
  #pragma unroll
  for(int o=32;o;o>>=1) v = fmaxf(v,__shfl_xor(v,o,64));
  return v;
}

// load 16 consecutive elements (weights, dtype per flag) into f32 regs
__device__ __forceinline__ void load16w(const void* W, long long eoff, int bf, float* x){
  if(bf){
    const uint4* q = (const uint4*)((const u16*)W + eoff);
    uint4 a = q[0], b = q[1];
    x[0]=bf2f(a.x&0xffffu); x[1]=bf2f(a.x>>16);
    x[2]=bf2f(a.y&0xffffu); x[3]=bf2f(a.y>>16);
    x[4]=bf2f(a.z&0xffffu); x[5]=bf2f(a.z>>16);
    x[6]=bf2f(a.w&0xffffu); x[7]=bf2f(a.w>>16);
    x[8]=bf2f(b.x&0xffffu); x[9]=bf2f(b.x>>16);
    x[10]=bf2f(b.y&0xffffu); x[11]=bf2f(b.y>>16);
    x[12]=bf2f(b.z&0xffffu); x[13]=bf2f(b.z>>16);
    x[14]=bf2f(b.w&0xffffu); x[15]=bf2f(b.w>>16);
  } else {
    const float4* q = (const float4*)((const float*)W + eoff);
    float4 A=q[0],B=q[1],C=q[2],D=q[3];
    x[0]=A.x;x[1]=A.y;x[2]=A.z;x[3]=A.w;
    x[4]=B.x;x[5]=B.y;x[6]=B.z;x[7]=B.w;
    x[8]=C.x;x[9]=C.y;x[10]=C.z;x[11]=C.w;
    x[12]=D.x;x[13]=D.y;x[14]=D.z;x[15]=D.w;
  }
}
__device__ __forceinline__ void load16f(const float* p, float* x){
  const float4* q=(const float4*)p;
  float4 A=q[0],B=q[1],C=q[2],D=q[3];
  x[0]=A.x;x[1]=A.y;x[2]=A.z;x[3]=A.w;
  x[4]=B.x;x[5]=B.y;x[6]=B.z;x[7]=B.w;
  x[8]=C.x;x[9]=C.y;x[10]=C.z;x[11]=C.w;
  x[12]=D.x;x[13]=D.y;x[14]=D.z;x[15]=D.w;
}
__device__ __forceinline__ float loadscal(const void* p, long long i, int bf){
  return bf ? bf2f(((const u16*)p)[i]) : ((const float*)p)[i];
}
__device__ __forceinline__ float sigf(float x){ return 1.f/(1.f+expf(-x)); }

__device__ __forceinline__ void dot4_accum(const float* w, const float xr[4][16], float a[4]){
  #pragma unroll
  for(int i=0;i<16;i++){
    a[0] += w[i]*xr[0][i];
    a[1] += w[i]*xr[1][i];
    a[2] += w[i]*xr[2][i];
    a[3] += w[i]*xr[3][i];
  }
}

// sorted-desc top4 insert, ties -> lower index (jax top_k semantics)
__device__ __forceinline__ void insert4(float* v, int* ix, float nv, int ni){
  bool b3 = (nv>v[3]) || (nv==v[3] && ni<ix[3]);
  if(!b3) return;
  bool b2 = (nv>v[2]) || (nv==v[2] && ni<ix[2]);
  bool b1 = (nv>v[1]) || (nv==v[1] && ni<ix[1]);
  bool b0 = (nv>v[0]) || (nv==v[0] && ni<ix[0]);
  if(b0){ v[3]=v[2];ix[3]=ix[2]; v[2]=v[1];ix[2]=ix[1]; v[1]=v[0];ix[1]=ix[0]; v[0]=nv;ix[0]=ni; }
  else if(b1){ v[3]=v[2];ix[3]=ix[2]; v[2]=v[1];ix[2]=ix[1]; v[1]=nv;ix[1]=ni; }
  else if(b2){ v[3]=v[2];ix[3]=ix[2]; v[2]=nv;ix[2]=ni; }
  else { v[3]=nv; ix[3]=ni; }
}
// merge two sorted-desc top4 lists
__device__ __forceinline__ void merge4(const float* va, const int* ia, const float* vb, const int* ib, float* vo, int* io){
  int pa=0, pb=0;
  for(int k=0;k<4;k++){
    bool ta;
    if(pa>=4) ta=false;
    else if(pb>=4) ta=true;
    else ta = (va[pa]>vb[pb]) || (va[pa]==vb[pb] && ia[pa]<ib[pb]);
    if(ta){ vo[k]=va[pa]; io[k]=ia[pa]; pa++; }
    else  { vo[k]=vb[pb]; io[k]=ib[pb]; pb++; }
  }
}

// device-scope grid barrier for co-resident blocks (monotonic counter)
__device__ __forceinline__ void gbar(int* cnt, int nblk, int it){
  __syncthreads();
  if(threadIdx.x==0){
    __hip_atomic_fetch_add(cnt, 1, __ATOMIC_ACQ_REL, __HIP_MEMORY_SCOPE_AGENT);
    int target = nblk*it;
    while(__hip_atomic_load(cnt, __ATOMIC_ACQUIRE, __HIP_MEMORY_SCOPE_AGENT) < target)
      __builtin_amdgcn_s_sleep(1);
  }
  __syncthreads();
  __builtin_amdgcn_fence(__ATOMIC_ACQUIRE, "agent");
}

// ---------------- dtype probe ----------------
__global__ __launch_bounds__(256) void k_probe(const u16* emb, int* flag, int* bar_cnt){
  __shared__ int cnt;
  if(threadIdx.x==0){ cnt=0; *bar_cnt=0; }
  __syncthreads();
  int c=0;
  for(int i=threadIdx.x;i<4096;i+=256){
    u32 e = (emb[i]>>7)&0xffu;
    if(e>=0x85u) c++;
  }
  atomicAdd(&cnt,c);
  __syncthreads();
  if(threadIdx.x==0) *flag = (cnt<100)?1:0;  // 1 = bf16, 0 = f32
}

// ---------------- encoder: gi = emb[seq] @ Wih^T + bih (batched over t) ----------------
__global__ __launch_bounds__(256) void k_enc_gi(const int* seq, const void* emb, const void* Wih,
                                                const void* bih, const int* flag, float* gi){
  int bf = *flag;
  int wg = blockIdx.x; int tg = wg>>3, rg = wg&7;
  int wave = threadIdx.x>>6, lane = threadIdx.x&63;
  int tok[4];
  #pragma unroll
  for(int j=0;j<4;j++) tok[j] = seq[tg*4+j];
  float xr[4][16];
  #pragma unroll
  for(int j=0;j<4;j++) load16w(emb, (long long)tok[j]*HDIM + lane*CHK, bf, xr[j]);
  for(int k=0;k<96;k++){
    int row = rg*384 + wave*96 + k;
    float w[16]; load16w(Wih, (long long)row*HDIM + lane*CHK, bf, w);
    float a[4]={0.f,0.f,0.f,0.f};
    dot4_accum(w, xr, a);
    float bias = loadscal(bih, row, bf);
    #pragma unroll
    for(int b=0;b<4;b++){
      float v = wred_sum(a[b]);
      if(lane==b) gi[(long long)(tg*4+b)*G3 + row] = v + bias;
    }
  }
}

// ---------------- persistent encoder recurrence: Whh held in registers ----------------
// 32 blocks x 512 threads = 256 waves; each wave owns 12 rows of Whh (12x16 f32 regs/lane);
// block owns output dims [blockIdx.x*32, +32). One grid barrier per step.
__global__ __launch_bounds__(512,2) void k_enc_persist(const void* Whh, const void* bhh,
                                                       const int* flag, const float* gi,
                                                       float* enc_out, int S, int* bar_cnt){
  int bf = *flag;
  int wave = threadIdx.x>>6, lane = threadIdx.x&63;
  int dbase = blockIdx.x*32;
  __shared__ float gh_s[96];
  __shared__ float bhh_s[96];
  if(threadIdx.x<96){
    int rl = threadIdx.x;
    int row = (rl>>5)*HDIM + dbase + (rl&31);
    bhh_s[rl] = loadscal(bhh, row, bf);
  }
  // preload weight slice into registers: rows wave*12..wave*12+11 of this block's 96
  float wreg[12][16];
  #pragma unroll
  for(int k=0;k<12;k++){
    int rl = wave*12 + k;
    int row = (rl>>5)*HDIM + dbase + (rl&31);
    load16w(Whh, (long long)row*HDIM + lane*CHK, bf, wreg[k]);
  }
  __syncthreads();

  for(int t=0;t<S;t++){
    if(t>0) gbar(bar_cnt, EB, t);   // enc_out[t-1] fully published
    float h[16];
    if(t>0){
      load16f(enc_out + (long long)(t-1)*HDIM + lane*CHK, h);
    } else {
      #pragma unroll
      for(int i=0;i<16;i++) h[i]=0.f;
    }
    #pragma unroll
    for(int k=0;k<12;k++){
      float a=0.f;
      #pragma unroll
      for(int i=0;i<16;i++) a += wreg[k][i]*h[i];
      a = wred_sum(a);
      if(lane==k) gh_s[wave*12+k] = a + bhh_s[wave*12+k];
    }
    __syncthreads();
    if(threadIdx.x<32){
      int d = threadIdx.x;
      int gd = dbase + d;
      const float* gir = gi + (long long)t*G3;
      float ir = gir[gd], iz = gir[HDIM+gd], in_ = gir[2*HDIM+gd];
      float hr = gh_s[d], hz = gh_s[32+d], hn = gh_s[64+d];
      float r = sigf(ir+hr);
      float z = sigf(iz+hz);
      float n = tanhf(in_ + r*hn);
      float hp = (t>0) ? enc_out[(long long)(t-1)*HDIM + gd] : 0.f;
      enc_out[(long long)t*HDIM + gd] = (1.f-z)*n + z*hp;
    }
    // gh_s reuse protected by next iteration's gbar __syncthreads
  }
}

// ---------------- decoder init ----------------
__global__ __launch_bounds__(256) void k_dec_init(const float* enc_out, int S, float* h_cur, float* cum,
                                                  int* cur_in, int* tokens, float* shist, int L){
  int t = threadIdx.x;
  const float* hf = enc_out + (long long)(S-1)*HDIM;
  for(int i=t;i<4*HDIM;i+=256) h_cur[i] = hf[i&(HDIM-1)];
  if(t<4){ cum[t]=0.f; cur_in[t]=1; }  // SOS=1
  for(int i=t;i<4*L;i+=256){ tokens[i]=0; shist[i]=0.f; }
}

// ---------------- decoder GRU step (all 4 beams) ----------------
__global__ __launch_bounds__(256) void k_dec_gru(const void* emb, const void* Wih, const void* Whh,
                                                 const void* bih, const void* bhh, const int* flag,
                                                 const int* cur_in, const float* h_cur, float* hnew){
  int bf = *flag;
  __shared__ float gibuf[96], ghbuf[96];
  int wave = threadIdx.x>>6, lane = threadIdx.x&63;
  int base = blockIdx.x*8;
  float xr[4][16];
  int tok[4];
  #pragma unroll
  for(int b=0;b<4;b++) tok[b]=cur_in[b];
  #pragma unroll
  for(int b=0;b<4;b++) load16w(emb,(long long)tok[b]*HDIM+lane*CHK,bf,xr[b]);
  for(int k=0;k<6;k++){
    int idx = wave*6+k; int g = idx>>3, d = idx&7;
    int row = g*HDIM + base + d;
    float w[16]; load16w(Wih,(long long)row*HDIM+lane*CHK,bf,w);
    float a[4]={0.f,0.f,0.f,0.f};
    dot4_accum(w,xr,a);
    float bias = loadscal(bih,row,bf);
    #pragma unroll
    for(int b=0;b<4;b++){
      float v = wred_sum(a[b]);
      if(lane==b) gibuf[idx*4+b] = v + bias;
    }
  }
  #pragma unroll
  for(int b=0;b<4;b++) load16f(h_cur+(long long)b*HDIM+lane*CHK, xr[b]);
  for(int k=0;k<6;k++){
    int idx = wave*6+k; int g = idx>>3, d = idx&7;
    int row = g*HDIM + base + d;
    float w[16]; load16w(Whh,(long long)row*HDIM+lane*CHK,bf,w);
    float a[4]={0.f,0.f,0.f,0.f};
    dot4_accum(w,xr,a);
    float bias = loadscal(bhh,row,bf);
    #pragma unroll
    for(int b=0;b<4;b++){
      float v = wred_sum(a[b]);
      if(lane==b) ghbuf[idx*4+b] = v + bias;
    }
  }
  __syncthreads();
  if(threadIdx.x<32){
    int d = threadIdx.x&7, b = threadIdx.x>>3;
    float ir = gibuf[(0*8+d)*4+b], iz = gibuf[(1*8+d)*4+b], in_ = gibuf[(2*8+d)*4+b];
    float hr = ghbuf[(0*8+d)*4+b], hz = ghbuf[(1*8+d)*4+b], hn = ghbuf[(2*8+d)*4+b];
    float r = sigf(ir+hr);
    float z = sigf(iz+hz);
    float n = tanhf(in_ + r*hn);
    float h = h_cur[b*HDIM + base + d];
    hnew[b*HDIM + base + d] = (1.f-z)*n + z*h;
  }
}

// ---------------- attention scores ----------------
__global__ __launch_bounds__(256) void k_dec_scores(const float* enc_out, const float* hnew, float* scores){
  int wave = threadIdx.x>>6, lane = threadIdx.x&63;
  float xr[4][16];
  #pragma unroll
  for(int b=0;b<4;b++) load16f(hnew+(long long)b*HDIM+lane*CHK, xr[b]);
  for(int k=0;k<4;k++){
    int s = (blockIdx.x*4+wave)*4+k;
    float w[16]; load16f(enc_out+(long long)s*HDIM+lane*CHK, w);
    float a[4]={0.f,0.f,0.f,0.f};
    dot4_accum(w,xr,a);
    #pragma unroll
    for(int b=0;b<4;b++){
      float v = wred_sum(a[b]);
      if(lane==b) scores[s*4+b] = v;
    }
  }
}

// ---------------- softmax + context ----------------
__global__ __launch_bounds__(256) void k_dec_attnctx(const float* enc_out, const float* scores_g,
                                                     float* ctx, int S){
  __shared__ float sc[256*4];
  int t = threadIdx.x;
  for(int i=t;i<S*4;i+=256) sc[i]=scores_g[i];
  __syncthreads();
  int wave = t>>6, lane = t&63;
  {
    int b = wave;
    float v[4];
    #pragma unroll
    for(int k=0;k<4;k++) v[k]=sc[(lane+64*k)*4+b];
    float m = fmaxf(fmaxf(v[0],v[1]),fmaxf(v[2],v[3]));
    m = wred_max(m);
    float e[4]; float ss=0.f;
    #pragma unroll
    for(int k=0;k<4;k++){ e[k]=expf(v[k]-m); ss+=e[k]; }
    ss = wred_sum(ss);
    #pragma unroll
    for(int k=0;k<4;k++) sc[(lane+64*k)*4+b] = e[k]/ss;
  }
  __syncthreads();
  int hl = t&127, bp = t>>7;
  int h = blockIdx.x*128 + hl;
  int b0 = bp*2;
  float a0=0.f, a1=0.f;
  for(int s=0;s<S;s++){
    float e = enc_out[(long long)s*HDIM + h];
    a0 += sc[s*4+b0]*e;
    a1 += sc[s*4+b0+1]*e;
  }
  ctx[b0*HDIM+h]=a0; ctx[(b0+1)*HDIM+h]=a1;
}

// ---------------- concat @ Wc^T, tanh ----------------
__global__ __launch_bounds__(256) void k_dec_wc(const void* Wc, const int* flag, const float* hnew,
                                                const float* ctx, float* concat){
  int bf = *flag;
  int wave = threadIdx.x>>6, lane = threadIdx.x&63;
  int r0 = blockIdx.x*16 + wave*4;
  float xr[4][16];
  #pragma unroll
  for(int b=0;b<4;b++) load16f(hnew+(long long)b*HDIM+lane*CHK, xr[b]);
  float acc[4][4];
  #pragma unroll
  for(int k=0;k<4;k++){
    #pragma unroll
    for(int b=0;b<4;b++) acc[k][b]=0.f;
  }
  #pragma unroll
  for(int k=0;k<4;k++){
    float w[16]; load16w(Wc,(long long)(r0+k)*2048 + lane*CHK, bf, w);
    #pragma unroll
    for(int i=0;i<16;i++){
      acc[k][0]+=w[i]*xr[0][i]; acc[k][1]+=w[i]*xr[1][i];
      acc[k][2]+=w[i]*xr[2][i]; acc[k][3]+=w[i]*xr[3][i];
    }
  }
  #pragma unroll
  for(int b=0;b<4;b++) load16f(ctx+(long long)b*HDIM+lane*CHK, xr[b]);
  #pragma unroll
  for(int k=0;k<4;k++){
    float w[16]; load16w(Wc,(long long)(r0+k)*2048 + 1024 + lane*CHK, bf, w);
    #pragma unroll
    for(int i=0;i<16;i++){
      acc[k][0]+=w[i]*xr[0][i]; acc[k][1]+=w[i]*xr[1][i];
      acc[k][2]+=w[i]*xr[2][i]; acc[k][3]+=w[i]*xr[3][i];
    }
  }
  #pragma unroll
  for(int k=0;k<4;k++){
    #pragma unroll
    for(int b=0;b<4;b++){
      float v = wred_sum(acc[k][b]);
      if(lane == k*4+b) concat[b*HDIM + r0 + k] = tanhf(v);
    }
  }
}

// ---------------- Wout logits + per-WG online max/sumexp/top4 (8 waves/block) ----------------
__global__ __launch_bounds__(512) void k_dec_logits(const void* Wout, const int* flag, const float* concat,
                                                    float* pm, float* ps, float* ptv, int* pti, int V){
  int bf = *flag;
  int wave = threadIdx.x>>6, lane = threadIdx.x&63;   // wave 0..7
  float xr[4][16];
  #pragma unroll
  for(int b=0;b<4;b++) load16f(concat+(long long)b*HDIM+lane*CHK, xr[b]);
  int wbase = blockIdx.x*125;
  int off  = (wave<5) ? wave*16 : 80 + (wave-5)*15;   // 5x16 + 3x15 = 125
  int cnt  = (wave<5) ? 16 : 15;
  float m[4], s[4], tv[4][4]; int ti_[4][4];
  #pragma unroll
  for(int b=0;b<4;b++){
    m[b]=NEG_INF; s[b]=0.f;
    #pragma unroll
    for(int j=0;j<4;j++){ tv[b][j]=NEG_INF; ti_[b][j]=0; }
  }
  for(int k=0;k<cnt;k++){
    int row = wbase + off + k;
    if(row>=V) break;
    float w[16]; load16w(Wout,(long long)row*HDIM+lane*CHK,bf,w);
    float a[4]={0.f,0.f,0.f,0.f};
    dot4_accum(w,xr,a);
    a[0]=wred_sum(a[0]); a[1]=wred_sum(a[1]); a[2]=wred_sum(a[2]); a[3]=wred_sum(a[3]);
    if(lane==0){
      #pragma unroll
      for(int b=0;b<4;b++){
        float v = a[b];
        if(v>m[b]){ s[b]=s[b]*expf(m[b]-v)+1.f; m[b]=v; }
        else s[b] += expf(v-m[b]);
        insert4(tv[b], ti_[b], v, row);
      }
    }
  }
  __shared__ float lm[32], lssum[32], ltv[128]; __shared__ int lti[128];
  if(lane==0){
    #pragma unroll
    for(int b=0;b<4;b++){
      lm[wave*4+b]=m[b]; lssum[wave*4+b]=s[b];
      #pragma unroll
      for(int j=0;j<4;j++){ ltv[(wave*4+b)*4+j]=tv[b][j]; lti[(wave*4+b)*4+j]=ti_[b][j]; }
    }
  }
  __syncthreads();
  if(threadIdx.x==0){
    for(int b=0;b<4;b++){
      float M=NEG_INF;
      for(int w=0;w<8;w++) M=fmaxf(M,lm[w*4+b]);
      float S=0.f;
      for(int w=0;w<8;w++) S += lssum[w*4+b]*expf(lm[w*4+b]-M);
      float cv[4]; int ci[4];
      for(int j=0;j<4;j++){ cv[j]=ltv[(0*4+b)*4+j]; ci[j]=lti[(0*4+b)*4+j]; }
      for(int w=1;w<8;w++){
        float vo[4]; int io[4];
        merge4(cv,ci,&ltv[(w*4+b)*4],&lti[(w*4+b)*4],vo,io);
        for(int j=0;j<4;j++){ cv[j]=vo[j]; ci[j]=io[j]; }
      }
      pm[blockIdx.x*4+b]=M; ps[blockIdx.x*4+b]=S;
      for(int j=0;j<4;j++){ ptv[(blockIdx.x*4+b)*4+j]=cv[j]; pti[(blockIdx.x*4+b)*4+j]=ci[j]; }
    }
  }
}

// ---------------- finalize: merge partials, beam update ----------------
__global__ __launch_bounds__(256) void k_dec_finalize(const float* pm, const float* ps, const float* ptv,
                                                      const int* pti, const float* hnew, float* h_cur,
                                                      float* cum, int* cur_in, int* tokens, float* shist,
                                                      int step, int L, const int* flag, void* dout){
  __shared__ float red[256];
  __shared__ float tpv[4][4]; __shared__ int tpi[4][4];
  __shared__ float logZ[4];
  __shared__ float mtv[256*4]; __shared__ int mti[256*4];
  __shared__ int l_bi[4], l_jj[4], l_tok[4]; __shared__ float l_ss[4], l_cum[4];
  __shared__ int otok[4*64]; __shared__ float oshi[4*64];
  __shared__ int bbest;
  int t = threadIdx.x;

  for(int b=0;b<4;b++){
    float v = pm[t*4+b];
    red[t]=v; __syncthreads();
    for(int st=128;st;st>>=1){ if(t<st) red[t]=fmaxf(red[t],red[t+st]); __syncthreads(); }
    float M = red[0]; __syncthreads();
    red[t] = ps[t*4+b]*expf(v-M); __syncthreads();
    for(int st=128;st;st>>=1){ if(t<st) red[t]+=red[t+st]; __syncthreads(); }
    if(t==0) logZ[b]=M+logf(red[0]);
    __syncthreads();
  }
  for(int b=0;b<4;b++){
    for(int j=0;j<4;j++){ mtv[t*4+j]=ptv[(t*4+b)*4+j]; mti[t*4+j]=pti[(t*4+b)*4+j]; }
    __syncthreads();
    for(int st=1; st<256; st<<=1){
      if((t & (2*st-1))==0 && t+st<256){
        float vo[4]; int io[4];
        merge4(&mtv[t*4], &mti[t*4], &mtv[(t+st)*4], &mti[(t+st)*4], vo, io);
        for(int j=0;j<4;j++){ mtv[t*4+j]=vo[j]; mti[t*4+j]=io[j]; }
      }
      __syncthreads();
    }
    if(t<4){ tpv[b][t]=mtv[t]-logZ[b]; tpi[b][t]=mti[t]; }
    __syncthreads();
  }
  if(t==0){
    float oc[4];
    for(int b=0;b<4;b++) oc[b]=cum[b];
    float cand[16];
    for(int b=0;b<4;b++)
      for(int j=0;j<4;j++){
        bool valid = (step>0)||(b==0);
        cand[b*4+j] = valid ? oc[b]+tpv[b][j] : NEG_INF;
      }
    bool used[16];
    for(int i=0;i<16;i++) used[i]=false;
    for(int q=0;q<4;q++){
      int best=0; float bv=NEG_INF;
      for(int i=0;i<16;i++){ if(!used[i] && cand[i]>bv){ bv=cand[i]; best=i; } }
      used[best]=true;
      int bi = best>>2, jj = best&3;
      l_bi[q]=bi; l_jj[q]=jj; l_tok[q]=tpi[bi][jj]; l_ss[q]=tpv[bi][jj]; l_cum[q]=bv;
    }
  }
  __syncthreads();
  for(int i=t;i<4*L;i+=256){ otok[i]=tokens[i]; oshi[i]=shist[i]; }
  __syncthreads();
  for(int i=t;i<4*L;i+=256){
    int q=i/L, c=i%L;
    int src=l_bi[q];
    tokens[i] = (c==step)? l_tok[q] : otok[src*L+c];
    shist[i]  = (c==step)? l_ss[q]  : oshi[src*L+c];
  }
  if(t<4){ cum[t]=l_cum[t]; cur_in[t]=l_tok[t]; }
  for(int i=t;i<4*HDIM;i+=256){
    int q=i>>10;
    h_cur[i] = hnew[l_jj[q]*HDIM + (i&(HDIM-1))];
  }
  if(step==L-1){
    if(t==0){
      int bb=0; float bv=l_cum[0];
      for(int b=1;b<4;b++) if(l_cum[b]>bv){ bv=l_cum[b]; bb=b; }
      bbest=bb;
    }
    __syncthreads();
    int bb=bbest; int bf=*flag;
    for(int c=t;c<L;c+=256){
      float tokv = (float)((c==step)? l_tok[bb] : otok[l_bi[bb]*L+c]);
      float shv  = (c==step)? l_ss[bb] : oshi[l_bi[bb]*L+c];
      if(bf){
        __hip_bfloat16* o = (__hip_bfloat16*)dout;
        o[c]   = __float2bfloat16(tokv);
        o[L+c] = __float2bfloat16(shv);
      } else {
        float* o = (float*)dout;
        o[c]   = tokv;
        o[L+c] = shv;
      }
    }
  }
}

extern "C" void kernel_launch(void* const* d_in, const int* in_sizes, int n_in,
                              void* d_out, int out_size, void* d_ws, size_t ws_size,
                              hipStream_t stream) {
  const int* seq   = (const int*)d_in[0];
  const void* emb  = d_in[3];
  const void* eWih = d_in[4]; const void* eWhh = d_in[5];
  const void* ebih = d_in[6]; const void* ebhh = d_in[7];
  const void* dWih = d_in[8]; const void* dWhh = d_in[9];
  const void* dbih = d_in[10]; const void* dbhh = d_in[11];
  const void* Wc   = d_in[12]; const void* Wout = d_in[13];

  int S = in_sizes[0];        // 256
  int L = out_size/2;         // 48
  int V = in_sizes[13]/HDIM;  // 32000

  char* p = (char*)d_ws;
  auto carve = [&](size_t bytes)->void* {
    void* r = (void*)p;
    p += (bytes + 255) & ~(size_t)255;
    return r;
  };
  int*   flag    = (int*)  carve(4);
  int*   bar_cnt = (int*)  carve(4);
  float* gi_enc  = (float*)carve((size_t)S*G3*4);
  float* enc_out = (float*)carve((size_t)S*HDIM*4);
  float* h_cur   = (float*)carve(4*HDIM*4);
  float* hnew    = (float*)carve(4*HDIM*4);
  float* scoresb = (float*)carve((size_t)S*4*4);
  float* ctx     = (float*)carve(4*HDIM*4);
  float* concat  = (float*)carve(4*HDIM*4);
  float* pm      = (float*)carve(256*4*4);
  float* ps      = (float*)carve(256*4*4);
  float* ptv     = (float*)carve(256*16*4);
  int*   pti     = (int*)  carve(256*16*4);
  float* cum     = (float*)carve(4*4);
  int*   cur_in  = (int*)  carve(4*4);
  int*   tokens  = (int*)  carve(4*L*4);
  float* shist   = (float*)carve(4*L*4);

  k_probe<<<1,256,0,stream>>>((const u16*)emb, flag, bar_cnt);
  k_enc_gi<<<(S/4)*8,256,0,stream>>>(seq, emb, eWih, ebih, flag, gi_enc);
  k_enc_persist<<<EB,512,0,stream>>>(eWhh, ebhh, flag, gi_enc, enc_out, S, bar_cnt);
  k_dec_init<<<1,256,0,stream>>>(enc_out, S, h_cur, cum, cur_in, tokens, shist, L);
  for(int st=0;st<L;st++){
    k_dec_gru<<<128,256,0,stream>>>(emb, dWih, dWhh, dbih, dbhh, flag, cur_in, h_cur, hnew);
    k_dec_scores<<<16,256,0,stream>>>(enc_out, hnew, scoresb);
    k_dec_attnctx<<<8,256,0,stream>>>(enc_out, scoresb, ctx, S);
    k_dec_wc<<<64,256,0,stream>>>(Wc, flag, hnew, ctx, concat);
    k_dec_logits<<<256,512,0,stream>>>(Wout, flag, concat, pm, ps, ptv, pti, V);
    k_dec_finalize<<<1,256,0,stream>>>(pm, ps, ptv, pti, hnew, h_cur, cum, cur_in,
                                       tokens, shist, st, L, flag, d_out);
  }
}